// Round 9
// baseline (144.340 us; speedup 1.0000x reference)
//
#include <hip/hip_runtime.h>
#include <hip/hip_bf16.h>

#define B_ 4
#define C_ 128
#define N_ 4096
#define M_ 4096

typedef __bf16 bf16;
typedef __bf16 bf16x8 __attribute__((ext_vector_type(8)));
typedef float f32x4 __attribute__((ext_vector_type(4)));
typedef float f32x16 __attribute__((ext_vector_type(16)));

#define MFMA16(a, b, c) __builtin_amdgcn_mfma_f32_16x16x32_bf16(a, b, c, 0, 0, 0)
#define MFMA32(a, b, c) __builtin_amdgcn_mfma_f32_32x32x16_bf16(a, b, c, 0, 0, 0)

// async 16B global -> LDS (dest = wave-uniform base + lane*16)
__device__ inline void gll16(const bf16* g, bf16* l) {
    __builtin_amdgcn_global_load_lds(
        (const __attribute__((address_space(1))) void*)g,
        (__attribute__((address_space(3))) void*)l, 16, 0, 0);
}

// v_cvt_pk_bf16_f32: pack two f32 -> u32 of 2 bf16 (lo = a, hi = b)
__device__ inline unsigned cvtpk(float a, float b) {
    unsigned r;
    asm("v_cvt_pk_bf16_f32 %0, %1, %2" : "=v"(r) : "v"(a), "v"(b));
    return r;
}

// ===========================================================================
// Kernel 0: one-shot W f32->bf16 conversion into the HEAD OF d_ws
// (attn reads Wq while writing out, so d_out parking would race).
// ===========================================================================
__global__ __launch_bounds__(256) void wcvt_kernel(
    const float* __restrict__ Wq, const float* __restrict__ Wk,
    const float* __restrict__ Wv, bf16* __restrict__ Wb) {
    int i = (blockIdx.x * 256 + threadIdx.x) * 4;        // 49152 elements total
    const float* src = (i < 16384) ? Wq : (i < 32768) ? Wk : Wv;
    int off = i & 16383;
    float4 v = *(const float4*)(src + off);
    union { ushort4 u4; bf16 h[4]; } pk;
    pk.h[0] = (bf16)v.x; pk.h[1] = (bf16)v.y;
    pk.h[2] = (bf16)v.z; pk.h[3] = (bf16)v.w;
    *(ushort4*)(Wb + i) = pk.u4;
}

// ===========================================================================
// Kernel 1: fused K+V projection. Grid (64 ntiles, 4 b), 512 thr (8 waves).
// ONE x2 tile load feeds BOTH the pos-folded (K) and raw (V) LDS tiles.
// Waves 0-3: K (swapped MFMA -> [m][c] stores, 32B segments); waves 4-7: V
// ([c][m] stores). Q-projection lives inside attn (block-local there).
// ===========================================================================
__global__ __launch_bounds__(512) void kvproj_kernel(
    const float* __restrict__ x2, const float* __restrict__ p2,
    const bf16* __restrict__ Wb, const float* __restrict__ Wpos,
    bf16* __restrict__ Kt, bf16* __restrict__ Vt) {
    __shared__ __align__(16) bf16 xp2[64 * 136];   // x2 + pos  [n][c]
    __shared__ __align__(16) bf16 xr2[64 * 136];   // x2 raw
    __shared__ float pp[3 * 64], wls[384];

    const int t = threadIdx.x;
    const int b = blockIdx.y;
    const int n0 = blockIdx.x * 64;

    // ---- phase A: stage p2 / Wpos ----
    if (t < 48) {
        int k3 = t / 16, i4 = (t & 15) * 4;
        *(float4*)&pp[k3 * 64 + i4] =
            *(const float4*)(p2 + ((size_t)b * 3 + k3) * N_ + n0 + i4);
    } else if (t < 144) {
        int i4 = (t - 48) * 4;
        *(float4*)&wls[i4] = *(const float4*)(Wpos + i4);
    }
    __syncthreads();

    // ---- phase B: one x2 load -> both tiles ----
    #pragma unroll
    for (int k = 0; k < 4; ++k) {
        int s = t + k * 512;
        int c = s >> 4, n4 = (s & 15) * 4;
        float4 xv = *(const float4*)(x2 + ((size_t)b * C_ + c) * N_ + n0 + n4);
        float w0 = wls[c * 3 + 0], w1 = wls[c * 3 + 1], w2 = wls[c * 3 + 2];
        const float* xa = &xv.x;
        #pragma unroll
        for (int j = 0; j < 4; ++j) {
            float pos = w0 * pp[n4 + j] + w1 * pp[64 + n4 + j] + w2 * pp[128 + n4 + j];
            xp2[(n4 + j) * 136 + c] = (bf16)(xa[j] + pos);
            xr2[(n4 + j) * 136 + c] = (bf16)xa[j];
        }
    }
    __syncthreads();

    // ---- phase C: waves 0-3 K, waves 4-7 V ----
    const int w = t >> 6;
    const int lane = t & 63;
    const int col = lane & 15, quad = lane >> 4;
    const int band = w & 3;
    const int nl = band * 16 + col;
    const bool isK = (w < 4);

    const bf16* src = isK ? xp2 : xr2;
    const bf16* Wm = Wb + (isK ? 16384 : 32768);   // Wk / Wv

    bf16x8 bx[4];
    #pragma unroll
    for (int cs = 0; cs < 4; ++cs)
        bx[cs] = *(const bf16x8*)&src[nl * 136 + cs * 32 + quad * 8];

    if (isK) {
        #pragma unroll
        for (int dt = 0; dt < 8; ++dt) {
            f32x4 acc = {0.f, 0.f, 0.f, 0.f};
            #pragma unroll
            for (int cs = 0; cs < 4; ++cs) {
                bf16x8 wf = *(const bf16x8*)(Wm + (dt * 16 + col) * 128 + cs * 32 + quad * 8);
                acc = MFMA16(bx[cs], wf, acc);        // SWAPPED: D[m-rows][c-cols]
            }
            #pragma unroll
            for (int r = 0; r < 4; ++r) {
                int n = n0 + band * 16 + quad * 4 + r;
                Kt[((size_t)b * N_ + n) * C_ + dt * 16 + col] = (bf16)acc[r];
            }
        }
    } else {
        #pragma unroll
        for (int dt = 0; dt < 8; ++dt) {
            f32x4 acc = {0.f, 0.f, 0.f, 0.f};
            #pragma unroll
            for (int cs = 0; cs < 4; ++cs) {
                bf16x8 wf = *(const bf16x8*)(Wm + (dt * 16 + col) * 128 + cs * 32 + quad * 8);
                acc = MFMA16(wf, bx[cs], acc);        // D[c-rows][m-cols]
            }
            #pragma unroll
            for (int r = 0; r < 4; ++r)
                Vt[((size_t)b * C_ + dt * 16 + quad * 4 + r) * (size_t)M_ + n0 + nl] = (bf16)acc[r];
        }
    }
}

// ===========================================================================
// Kernel 2: attn with IN-KERNEL Q PROJECTION prologue (Q is block-local:
// each block's 64 queries need only its x1 tile + p1 + Wq). Deletes the Qt
// HBM roundtrip and a third of the old proj grid. K/V pipeline, softmax,
// and epilogue identical to the round-6/7 verified kernel.
// ===========================================================================
__global__ __launch_bounds__(512) void attn_kernel(
    const bf16* __restrict__ Kt, const bf16* __restrict__ Vt,
    const float* __restrict__ x1, const float* __restrict__ p1,
    const bf16* __restrict__ Wb, const float* __restrict__ Wpos,
    float* __restrict__ out) {
    __shared__ __align__(16) char smem[132096];
    // main loop: kb0 @0, kb1 @32768; vb0 @65536, vb1 @98304
    // prologue (inside kb0 region, consumed before staging): xq @0 (17408 B),
    //   ppq @17408 (768 B), wlsq @18176 (1536 B)

    const int t = threadIdx.x;
    const int w = t >> 6;
    const int lane = t & 63;
    const int col = lane & 31;
    const int hi = lane >> 5;
    const int kg = w & 3;            // key-group (32 keys of 128-key chunk)
    const int qg = w >> 2;           // query-group (32 of the 64 queries)

    // XCD-aware decode: batch -> XCD pair (K+V of one batch L2-resident)
    const int g0 = blockIdx.x;
    const int xcd = g0 & 7;
    const int b = xcd >> 1;
    const int qt = (xcd & 1) + ((g0 >> 3) << 1);   // 64 q-tiles of 64
    const int n0 = qt * 64;

    const float KS = 0.12752107168406815f;  // log2(e)/sqrt(128)

    const bf16* Kbase = Kt + (size_t)b * M_ * C_;
    const bf16* Vbase = Vt + (size_t)b * C_ * M_;

    // ======================= Q-projection prologue =======================
    bf16* xq = (bf16*)smem;                    // [64][136]
    float* ppq = (float*)(smem + 17408);
    float* wlsq = (float*)(smem + 18176);

    if (t < 48) {
        int k3 = t / 16, i4 = (t & 15) * 4;
        *(float4*)&ppq[k3 * 64 + i4] =
            *(const float4*)(p1 + ((size_t)b * 3 + k3) * N_ + n0 + i4);
    } else if (t < 144) {
        int i4 = (t - 48) * 4;
        *(float4*)&wlsq[i4] = *(const float4*)(Wpos + i4);
    }
    __syncthreads();

    #pragma unroll
    for (int k = 0; k < 4; ++k) {
        int s = t + k * 512;
        int c = s >> 4, n4 = (s & 15) * 4;
        float4 xv = *(const float4*)(x1 + ((size_t)b * C_ + c) * N_ + n0 + n4);
        float w0 = wlsq[c * 3 + 0], w1 = wlsq[c * 3 + 1], w2 = wlsq[c * 3 + 2];
        const float* xa = &xv.x;
        #pragma unroll
        for (int j = 0; j < 4; ++j) {
            float pos = w0 * ppq[n4 + j] + w1 * ppq[64 + n4 + j] + w2 * ppq[128 + n4 + j];
            xq[(n4 + j) * 136 + c] = (bf16)(xa[j] + pos);
        }
    }
    __syncthreads();

    {   // 8 waves: band = w&3 (16 q-points), dt-half = w>>2 (4 of 8 dts)
        const int colq = lane & 15, quadq = lane >> 4;
        const int nlq = (w & 3) * 16 + colq;
        bf16x8 bxq[4];
        #pragma unroll
        for (int cs = 0; cs < 4; ++cs)
            bxq[cs] = *(const bf16x8*)&xq[nlq * 136 + cs * 32 + quadq * 8];
        __syncthreads();               // fragment reads done before Q overwrites xq
        const int dt0 = (w >> 2) * 4;
        #pragma unroll
        for (int di = 0; di < 4; ++di) {
            int dt = dt0 + di;
            f32x4 acc = {0.f, 0.f, 0.f, 0.f};
            #pragma unroll
            for (int cs = 0; cs < 4; ++cs) {
                bf16x8 wf = *(const bf16x8*)(Wb + (dt * 16 + colq) * 128 + cs * 32 + quadq * 8);
                acc = MFMA16(bxq[cs], wf, acc);       // D[q-rows][c-cols]
            }
            #pragma unroll
            for (int r = 0; r < 4; ++r)
                xq[((w & 3) * 16 + quadq * 4 + r) * 136 + dt * 16 + colq] = (bf16)acc[r];
        }
        __syncthreads();               // Q tile complete
    }

    // Q fragments (B-operand of swapped QK): lane col = query, k = hi*8+j
    bf16x8 qf[8];
    #pragma unroll
    for (int cs = 0; cs < 8; ++cs)
        qf[cs] = *(const bf16x8*)&xq[(qg * 32 + col) * 136 + cs * 16 + hi * 8];
    asm volatile("s_waitcnt lgkmcnt(0)" ::: "memory");
    __builtin_amdgcn_sched_barrier(0);
    __builtin_amdgcn_s_barrier();      // all qf reads retired before staging lands
    // =====================================================================

    f32x16 oacc[4];
    #pragma unroll
    for (int i = 0; i < 4; ++i)
        #pragma unroll
        for (int j = 0; j < 16; ++j) oacc[i][j] = 0.f;
    float lacc = 0.f;

    const int key_l = (kg << 5) + col;
    const int kxor = (key_l & 15) << 4;

    // running staging pointers (pre-swizzled source addressing)
    const bf16* kpp[4];
    const bf16* vpp[4];
    #pragma unroll
    for (int i = 0; i < 4; ++i) {
        int g = ((w << 2) + i) * 64 + lane;
        int row = g >> 4;                    // key (K) / channel (V)
        int sp = (g & 15) ^ (row & 15);      // inverse-swizzled SOURCE slot
        kpp[i] = Kbase + (size_t)row * C_ + sp * 8;
        vpp[i] = Vbase + (size_t)row * M_ + sp * 8;
    }

    auto stageK = [&](char* dst) {
        #pragma unroll
        for (int i = 0; i < 4; ++i) {
            gll16(kpp[i], (bf16*)dst + ((w << 2) + i) * 512);
            kpp[i] += 128 * C_;              // next 128-key chunk
        }
    };
    auto stageV = [&](char* dst) {
        #pragma unroll
        for (int i = 0; i < 4; ++i) {
            gll16(vpp[i], (bf16*)dst + ((w << 2) + i) * 512);
            vpp[i] += 128;                   // next 128-key chunk (col shift)
        }
    };

    // prologue FIFO: K0 -> kb0, V0 -> vb0, K1 -> kb1   (12 loads)
    stageK(smem);
    stageV(smem + 65536);
    stageK(smem + 32768);

    f32x16 sA0, sA1, sB0, sB1;

    // QK MFMA cluster: chunk read from kbBuf -> (T0,T1)
    auto qkc = [&](const char* kbBuf, f32x16& T0, f32x16& T1) {
        #pragma unroll
        for (int q = 0; q < 16; ++q) { T0[q] = 0.f; T1[q] = 0.f; }
        const char* kbp = kbBuf + key_l * 256;
        __builtin_amdgcn_s_setprio(1);
        #pragma unroll
        for (int cs = 0; cs < 4; ++cs) {
            bf16x8 kf = *(const bf16x8*)(kbp + ((((cs << 1) + hi) << 4) ^ kxor));
            T0 = MFMA32(kf, qf[cs], T0);
        }
        #pragma unroll
        for (int cs = 4; cs < 8; ++cs) {
            bf16x8 kf = *(const bf16x8*)(kbp + ((((cs << 1) + hi) << 4) ^ kxor));
            T1 = MFMA32(kf, qf[cs], T1);
        }
        __builtin_amdgcn_s_setprio(0);
    };

    // SM(j) from (S0,S1) -> af0/af1 ; PV(j) from vbBuf
    auto smpv = [&](f32x16& S0, f32x16& S1, const char* vbBuf) {
        float p[16];
        #pragma unroll
        for (int r = 0; r < 16; ++r) {
            float e = fminf((S0[r] + S1[r]) * KS, 60.f);
            p[r] = __builtin_amdgcn_exp2f(e);
        }
        {
            float s01 = (p[0] + p[1]) + (p[2] + p[3]);
            float s23 = (p[4] + p[5]) + (p[6] + p[7]);
            float s45 = (p[8] + p[9]) + (p[10] + p[11]);
            float s67 = (p[12] + p[13]) + (p[14] + p[15]);
            lacc += (s01 + s23) + (s45 + s67);
        }
        unsigned W0 = cvtpk(p[0], p[1]),  W1 = cvtpk(p[2], p[3]);
        unsigned W2 = cvtpk(p[4], p[5]),  W3 = cvtpk(p[6], p[7]);
        unsigned W4 = cvtpk(p[8], p[9]),  W5 = cvtpk(p[10], p[11]);
        unsigned W6 = cvtpk(p[12], p[13]), W7 = cvtpk(p[14], p[15]);
        unsigned X0 = hi ? W0 : W2, X1 = hi ? W1 : W3;
        unsigned Y0 = hi ? W4 : W6, Y1 = hi ? W5 : W7;
        X0 = __shfl_xor(X0, 32, 64);  X1 = __shfl_xor(X1, 32, 64);
        Y0 = __shfl_xor(Y0, 32, 64);  Y1 = __shfl_xor(Y1, 32, 64);
        uint4 u0, u1;
        u0.x = hi ? X0 : W0;  u0.y = hi ? X1 : W1;
        u0.z = hi ? W2 : X0;  u0.w = hi ? W3 : X1;
        u1.x = hi ? Y0 : W4;  u1.y = hi ? Y1 : W5;
        u1.z = hi ? W6 : Y0;  u1.w = hi ? W7 : Y1;
        bf16x8 af0 = __builtin_bit_cast(bf16x8, u0);   // keys hi*8   .. +7
        bf16x8 af1 = __builtin_bit_cast(bf16x8, u1);   // keys 16+hi*8.. +7

        __builtin_amdgcn_s_setprio(1);
        #pragma unroll
        for (int ct = 0; ct < 4; ++ct) {
            int c = (ct << 5) + col;
            const char* vbp = vbBuf + c * 256;
            int vxor = (c & 15) << 4;
            bf16x8 vf0 = *(const bf16x8*)(vbp + ((((kg << 2) + hi) << 4) ^ vxor));
            bf16x8 vf1 = *(const bf16x8*)(vbp + ((((kg << 2) + 2 + hi) << 4) ^ vxor));
            oacc[ct] = MFMA32(af0, vf0, oacc[ct]);
            oacc[ct] = MFMA32(af1, vf1, oacc[ct]);
        }
        __builtin_amdgcn_s_setprio(0);
    };

    // peel: K0 landed for everyone -> compute S(0)
    asm volatile("s_waitcnt vmcnt(8)" ::: "memory");
    __builtin_amdgcn_sched_barrier(0);
    __builtin_amdgcn_s_barrier();
    __builtin_amdgcn_sched_barrier(0);
    qkc(smem, sA0, sA1);

    for (int jp = 0; jp < 16; ++jp) {
        const int j0 = jp * 2, j1 = j0 + 1;

        // ---- body A (even j0): SM/PV on j0 with S=A, QK(j0+1)->B ----
        asm volatile("s_waitcnt vmcnt(0)" ::: "memory");   // V(j0), K(j0+1) landed
        __builtin_amdgcn_sched_barrier(0);
        __builtin_amdgcn_s_barrier();                      // published; prev reads retired
        __builtin_amdgcn_sched_barrier(0);
        if (j0 < 31) stageV(smem + 98304);                 // V(j0+1) -> vb1
        if (j0 < 30) stageK(smem);                         // K(j0+2) -> kb0
        if (j0 < 31) qkc(smem + 32768, sB0, sB1);          // QK(j0+1) from kb1
        smpv(sA0, sA1, smem + 65536);                      // SM(j0)+PV(j0), vb0
        asm volatile("s_waitcnt lgkmcnt(0)" ::: "memory");
        __builtin_amdgcn_sched_barrier(0);

        // ---- body B (odd j1): SM/PV on j1 with S=B, QK(j1+1)->A ----
        asm volatile("s_waitcnt vmcnt(0)" ::: "memory");   // V(j1), K(j1+1) landed
        __builtin_amdgcn_sched_barrier(0);
        __builtin_amdgcn_s_barrier();
        __builtin_amdgcn_sched_barrier(0);
        if (j1 < 31) stageV(smem + 65536);                 // V(j1+1) -> vb0
        if (j1 < 30) stageK(smem + 32768);                 // K(j1+2) -> kb1
        if (j1 < 31) qkc(smem, sA0, sA1);                  // QK(j1+1) from kb0
        smpv(sB0, sB1, smem + 98304);                      // SM(j1)+PV(j1), vb1
        asm volatile("s_waitcnt lgkmcnt(0)" ::: "memory");
        __builtin_amdgcn_sched_barrier(0);
    }

    __builtin_amdgcn_s_barrier();   // all LDS reads retired; reuse smem

    // ---- cross-wave merge of key-group partials ----
    float* obuf = (float*)smem;                 // [4 kg][64 q][128 c]  128 KB
    float* lps  = (float*)(smem + 131072);      // [4 kg][64 q]  1 KB (fits)

    lacc += __shfl_xor(lacc, 32, 64);           // + other hi-half's 16 keys
    if (hi == 0) lps[(kg << 6) + (qg << 5) + col] = lacc;

    #pragma unroll
    for (int ct = 0; ct < 4; ++ct)
        #pragma unroll
        for (int r = 0; r < 16; ++r) {
            int q = (r & 3) + ((r >> 2) << 3) + (hi << 2);
            obuf[kg * 8192 + ((qg << 5) + q) * 128 + (ct << 5) + col] = oacc[ct][r];
        }
    __syncthreads();

    const int c2 = lane << 1;                   // 2 channels per lane
    #pragma unroll
    for (int j = 0; j < 8; ++j) {
        int q = (w << 3) + j;                   // wave w finalizes queries w*8..+7
        float s0 = 0.f, s1 = 0.f;
        #pragma unroll
        for (int pp = 0; pp < 4; ++pp) {
            float2 v = *(const float2*)&obuf[pp * 8192 + q * 128 + c2];
            s0 += v.x; s1 += v.y;
        }
        float lsum = lps[q] + lps[64 + q] + lps[128 + q] + lps[192 + q];
        float linv = 1.0f / lsum;
        int n = n0 + q;
        float o0 = s0 * linv + x1[((size_t)b * C_ + c2) * N_ + n];
        float o1 = s1 * linv + x1[((size_t)b * C_ + c2 + 1) * N_ + n];
        *(float2*)&out[((size_t)b * N_ + n) * C_ + c2] = make_float2(o0, o1);
    }
}

// ---------------------------------------------------------------------------
extern "C" void kernel_launch(void* const* d_in, const int* in_sizes, int n_in,
                              void* d_out, int out_size, void* d_ws, size_t ws_size,
                              hipStream_t stream) {
    const float* x1   = (const float*)d_in[0];
    const float* p1   = (const float*)d_in[1];
    const float* x2   = (const float*)d_in[2];
    const float* p2   = (const float*)d_in[3];
    const float* Wq   = (const float*)d_in[4];
    const float* Wk   = (const float*)d_in[5];
    const float* Wv   = (const float*)d_in[6];
    const float* Wpos = (const float*)d_in[7];
    float* out = (float*)d_out;

    // d_ws layout: Wb (128 KB region) | Kt [B][M][C] 4 MB | Vt [B][C][M] 4 MB
    bf16* Wb = (bf16*)d_ws;
    bf16* Kt = Wb + 65536;
    bf16* Vt = Kt + (size_t)B_ * M_ * C_;

    wcvt_kernel<<<dim3(48), dim3(256), 0, stream>>>(Wq, Wk, Wv, Wb);
    kvproj_kernel<<<dim3(64, B_), dim3(512), 0, stream>>>(
        x2, p2, Wb, Wpos, Kt, Vt);
    attn_kernel<<<dim3(256), dim3(512), 0, stream>>>(
        Kt, Vt, x1, p1, Wb, Wpos, out);
}